// Round 11
// baseline (547.766 us; speedup 1.0000x reference)
//
#include <hip/hip_runtime.h>

// RiskGCN: 3-layer GCNConv (self-loops, sym deg^-1/2 norm) + mean pool + linear head.
// N=100000 nodes, E=1.6M edges, D=128, 256 graphs.
// CSR build: bucket-scatter (k_bucketA) -> per-bucket degree hist (k_degB) ->
// scan -> counting-sort (k_bucketB).
// Layers 1-2: MFMA bf16 GEMM -> XCD-sliced gather-agg: T/H stored [8][N][16],
// group = blockIdx%8 so each XCD's L2 holds one 3.2MB slice (fits 4MB).
// Layer 3: GEMM writes row-major T; agg fuses per-node head dot; segment
// reduce finishes mean+bias.

#define D 128
#define NB_SHIFT 8            // 256 nodes per bucket
#define BCAP 8192             // arena stride per bucket; mean 4096, 64 sigma headroom
#define EPB 4096              // edges per block in bucket pass A (391 blocks)
// NOTE: packing assumes N <= 2^17 and nodes-per-bucket <= 256.

typedef unsigned int uint;
typedef unsigned short ushort;
typedef __attribute__((ext_vector_type(8))) short short8;
typedef __attribute__((ext_vector_type(4))) float f32x4;

__device__ __forceinline__ ushort f2bf(float f) {
    uint u = __float_as_uint(f);
    uint r = (u + 0x7fffu + ((u >> 16) & 1u)) >> 16;   // RNE
    return (ushort)r;
}
__device__ __forceinline__ float bf2f(ushort b) {
    return __uint_as_float(((uint)b) << 16);
}
// 15-bit float norm decode: 5 LSBs of exponent + 10 mantissa bits, exp base 96.
__device__ __forceinline__ float q15f(uint q) {
    return __uint_as_float(0x30000000u | (q << 13));
}

// async 16B global->LDS copy (lds dest is wave-uniform base; HW adds lane*16)
__device__ __forceinline__ void async_cp16(const ushort* g, ushort* lds_uniform) {
    __builtin_amdgcn_global_load_lds(
        (const __attribute__((address_space(1))) unsigned int*)g,
        (__attribute__((address_space(3))) unsigned int*)lds_uniform,
        16, 0, 0);
}

// ---------------- bucket pass A: scatter edges into per-bucket arenas ----------------
// Entry: (dlocal << 17) | src.
__global__ __launch_bounds__(256) void k_bucketA(const int* __restrict__ src,
                                                 const int* __restrict__ dst, int E,
                                                 int nbk, int* __restrict__ gcur,
                                                 uint* __restrict__ arena) {
    __shared__ int hist[512];
    __shared__ int rbase[512];
    int t = threadIdx.x;
    int e0 = blockIdx.x * EPB;
    int e1 = min(e0 + EPB, E);
    for (int i = t; i < nbk; i += 256) hist[i] = 0;
    __syncthreads();
    for (int e = e0 + t; e < e1; e += 256)
        atomicAdd(&hist[dst[e] >> NB_SHIFT], 1);
    __syncthreads();
    for (int i = t; i < nbk; i += 256) {
        int c = hist[i];
        rbase[i] = (c > 0) ? atomicAdd(&gcur[i], c) : 0;
        hist[i] = 0;   // reuse as local cursor
    }
    __syncthreads();
    for (int e = e0 + t; e < e1; e += 256) {
        int d = dst[e];
        int s = src[e];
        int b = d >> NB_SHIFT;
        int pos = rbase[b] + atomicAdd(&hist[b], 1);
        if (pos < BCAP)
            arena[(size_t)b * BCAP + pos] =
                ((uint)(d & ((1 << NB_SHIFT) - 1)) << 17) | (uint)s;
    }
}

// ---------------- per-bucket degree histogram ----------------
__global__ __launch_bounds__(256) void k_degB(const uint* __restrict__ arena,
                                              const int* __restrict__ gcur, int N,
                                              int* __restrict__ degi,
                                              float* __restrict__ dinv) {
    int b = blockIdx.x;
    int t = threadIdx.x;
    __shared__ int hist[256];
    hist[t] = 0;
    __syncthreads();
    int cnt = min(gcur[b], BCAP);
    const uint* seg = arena + (size_t)b * BCAP;
    for (int i = t; i < cnt; i += 256)
        atomicAdd(&hist[seg[i] >> 17], 1);
    __syncthreads();
    int node = (b << NB_SHIFT) + t;
    if (node < N) {
        int c = hist[t];
        degi[node] = c;
        dinv[node] = rsqrtf((float)(c + 1));   // +1 self-loop
    }
}

// ---------------- exclusive scan of degi -> row_start ----------------
__global__ void k_scan1(const int* __restrict__ cnt, int N, int* __restrict__ bsum) {
    __shared__ int sdata[256];
    int t = threadIdx.x;
    int base = blockIdx.x * 1024 + t * 4;
    int s = 0;
#pragma unroll
    for (int j = 0; j < 4; j++) { int i = base + j; if (i < N) s += cnt[i]; }
    sdata[t] = s; __syncthreads();
    for (int off = 128; off > 0; off >>= 1) {
        if (t < off) sdata[t] += sdata[t + off];
        __syncthreads();
    }
    if (t == 0) bsum[blockIdx.x] = sdata[0];
}

__global__ void k_scan2(int* __restrict__ bsum, int nb) {
    if (threadIdx.x == 0) {
        int run = 0;
        for (int b = 0; b < nb; b++) { int v = bsum[b]; bsum[b] = run; run += v; }
    }
}

__global__ void k_scan3(const int* __restrict__ cnt, int N, const int* __restrict__ bofs,
                        int* __restrict__ row_start, int E) {
    __shared__ int sdata[256];
    int t = threadIdx.x;
    int base = blockIdx.x * 1024 + t * 4;
    int v[4]; int s = 0;
#pragma unroll
    for (int j = 0; j < 4; j++) { int i = base + j; v[j] = (i < N) ? cnt[i] : 0; s += v[j]; }
    sdata[t] = s; __syncthreads();
    for (int off = 1; off < 256; off <<= 1) {
        int x = (t >= off) ? sdata[t - off] : 0;
        __syncthreads();
        sdata[t] += x;
        __syncthreads();
    }
    int excl = (t == 0) ? 0 : sdata[t - 1];
    int run = bofs[blockIdx.x] + excl;
#pragma unroll
    for (int j = 0; j < 4; j++) {
        int i = base + j;
        if (i < N) row_start[i] = run;
        run += v[j];
    }
    if (blockIdx.x == 0 && t == 0) row_start[N] = E;
}

// ---------------- bucket pass B: counting-sort bucket into CSR via LDS ----------------
__global__ __launch_bounds__(256) void k_bucketB(const uint* __restrict__ arena,
                                                 const int* __restrict__ gcur,
                                                 const int* __restrict__ row_start,
                                                 const float* __restrict__ dinv,
                                                 int N, uint* __restrict__ csr) {
    int b = blockIdx.x;
    int t = threadIdx.x;
    int n0 = b << NB_SHIFT;
    int nn = min(1 << NB_SHIFT, N - n0);
    __shared__ float sdinv[256];
    __shared__ int sstart[256];
    __shared__ int scur[256];
    __shared__ uint sout[BCAP];   // 32 KB
    for (int i = t; i < nn; i += 256) {
        sdinv[i]  = dinv[n0 + i];
        sstart[i] = row_start[n0 + i];
        scur[i]   = 0;
    }
    __syncthreads();
    int cnt = min(gcur[b], BCAP);
    int csr0 = sstart[0];
    for (int i = t; i < cnt; i += 256) {
        uint en = arena[(size_t)b * BCAP + i];
        int dl = en >> 17;
        int s  = en & 0x1FFFF;
        float nrm = dinv[s] * sdinv[dl];
        uint q = ((__float_as_uint(nrm) + 0x1000u) >> 13) & 0x7FFFu;
        int pos = atomicAdd(&scur[dl], 1);
        sout[(sstart[dl] - csr0) + pos] = ((uint)s << 15) | q;
    }
    __syncthreads();
    for (int i = t; i < cnt; i += 256)
        csr[csr0 + i] = sout[i];
}

// ---------------- W split+fragment: Wfrag[h][kt][nt][lane][8] bf16 ----------------
__global__ void k_wsplit(const float* __restrict__ W, ushort* __restrict__ Wf) {
    int idx = blockIdx.x * blockDim.x + threadIdx.x;   // 32768 total
    if (idx >= 32768) return;
    int i  = idx & 7;
    int l  = (idx >> 3) & 63;
    int nt = (idx >> 9) & 7;
    int kt = (idx >> 12) & 3;
    int h  = idx >> 14;
    int k = kt * 32 + (l >> 4) * 8 + i;
    int n = nt * 16 + (l & 15);
    float w = W[k * D + n];
    ushort hi = f2bf(w);
    ushort v = (h == 0) ? hi : f2bf(w - bf2f(hi));
    Wf[idx] = v;
}

// ---------------- MFMA GEMM: T = A @ W (layouts templated) ----------------
// IN_MODE:  0 = f32 row-major [N][128] (layer 1), 1 = bf16 sliced [8][N][16].
// OUT_MODE: 0 = bf16 row-major [N][128] (layer 3), 1 = bf16 sliced [8][N][16].
// 256 thr (4 waves), 64-row tile; wave owns nt = 2w, 2w+1; B preloaded once;
// A via swizzled LDS (async global_load_lds for bf16 input, pre-swizzled src).
template <int IN_MODE, int OUT_MODE>
__global__ __launch_bounds__(256) void k_gemm(const void* __restrict__ Ain,
                                              const ushort* __restrict__ Wf,
                                              ushort* __restrict__ out, int N) {
    __shared__ ushort As[64 * D];   // 16 KB, swizzled
    int t = threadIdx.x;
    int rowb = blockIdx.x * 64;
    size_t sliceN = (size_t)N * 16;

    if (IN_MODE == 0) {
        const float* A = (const float*)Ain;
#pragma unroll
        for (int i = 0; i < 8; i++) {
            int u = i * 256 + t;
            int row = u >> 5, c4 = u & 31;
            int grow = rowb + row;
            float4 v = make_float4(0.f, 0.f, 0.f, 0.f);
            if (grow < N) v = *(const float4*)(A + (size_t)grow * D + c4 * 4);
            uint2 p;
            p.x = (uint)f2bf(v.x) | ((uint)f2bf(v.y) << 16);
            p.y = (uint)f2bf(v.z) | ((uint)f2bf(v.w) << 16);
            int byteoff = row * 256 + ((c4 * 8) ^ ((row & 7) << 4));
            *(uint2*)((char*)As + byteoff) = p;
        }
    } else {
        const ushort* A = (const ushort*)Ain;
        // chunk u = (row, c'); source chunk gc = c' ^ (row&7) (inverse of read XOR);
        // sliced addr: group gc>>1, half gc&1.
#pragma unroll
        for (int i = 0; i < 4; i++) {
            int u = i * 256 + t;
            int row = u >> 4, cp = u & 15;
            int grow = rowb + row;
            if (grow >= N) grow = N - 1;          // clamp; rows discarded at store
            int gc = cp ^ (row & 7);
            const ushort* gp = A + (size_t)(gc >> 1) * sliceN
                                 + (size_t)grow * 16 + (gc & 1) * 8;
            ushort* lb = As + (size_t)(i * 256 + (t & 192)) * 8;
            async_cp16(gp, lb);
        }
        asm volatile("s_waitcnt vmcnt(0)" ::: "memory");
    }
    __syncthreads();

    int wave = t >> 6, lane = t & 63;
    const short8* Wf8 = (const short8*)Wf;

    short8 bhi[2][4], blo[2][4];
#pragma unroll
    for (int j = 0; j < 2; j++) {
        int nt = wave * 2 + j;
#pragma unroll
        for (int kt = 0; kt < 4; kt++) {
            bhi[j][kt] = Wf8[(size_t)((0 * 4 + kt) * 8 + nt) * 64 + lane];
            blo[j][kt] = Wf8[(size_t)((1 * 4 + kt) * 8 + nt) * 64 + lane];
        }
    }

    f32x4 acc[4][2];
#pragma unroll
    for (int m = 0; m < 4; m++)
#pragma unroll
        for (int j = 0; j < 2; j++) acc[m][j] = (f32x4){0.f, 0.f, 0.f, 0.f};

#pragma unroll
    for (int m = 0; m < 4; m++) {
        int r = m * 16 + (lane & 15);
#pragma unroll
        for (int kt = 0; kt < 4; kt++) {
            int raw = kt * 64 + (lane >> 4) * 16;
            short8 a = *(const short8*)((const char*)As + r * 256 + (raw ^ ((r & 7) << 4)));
#pragma unroll
            for (int j = 0; j < 2; j++) {
                acc[m][j] = __builtin_amdgcn_mfma_f32_16x16x32_bf16(a, bhi[j][kt], acc[m][j], 0, 0, 0);
                acc[m][j] = __builtin_amdgcn_mfma_f32_16x16x32_bf16(a, blo[j][kt], acc[m][j], 0, 0, 0);
            }
        }
    }

    // C/D: col = lane&15, row = (lane>>4)*4 + jj
#pragma unroll
    for (int m = 0; m < 4; m++) {
#pragma unroll
        for (int j = 0; j < 2; j++) {
            int colb = (wave * 2 + j) * 16 + (lane & 15);
#pragma unroll
            for (int jj = 0; jj < 4; jj++) {
                int grow = rowb + m * 16 + (lane >> 4) * 4 + jj;
                if (grow < N) {
                    if (OUT_MODE == 0)
                        out[(size_t)grow * D + colb] = f2bf(acc[m][j][jj]);
                    else
                        out[(size_t)(colb >> 4) * sliceN + (size_t)grow * 16 + (colb & 15)]
                            = f2bf(acc[m][j][jj]);
                }
            }
        }
    }
}

// ---------------- XCD-sliced aggregation (layers 1-2) ----------------
// T,H in [8][N][16] layout; group = blockIdx%8 -> one 3.2MB slice per XCD L2.
// 8 lanes per node, lane k covers cols 2k,2k+1 of the group; unroll-4 edge loop.
// csr stream + H store nontemporal so they don't evict the slice.
__global__ __launch_bounds__(256) void k_agg_sliced(const ushort* __restrict__ T,
                                                    const float* __restrict__ dinv,
                                                    const int* __restrict__ row_start,
                                                    const uint* __restrict__ csr,
                                                    const float* __restrict__ bias,
                                                    ushort* __restrict__ out, int N) {
    int g = blockIdx.x & 7;
    int node = (blockIdx.x >> 3) * 32 + (threadIdx.x >> 3);
    if (node >= N) return;
    int k = threadIdx.x & 7;
    size_t sliceN = (size_t)N * 16;
    const ushort* Tg = T + (size_t)g * sliceN;
    ushort* Hg = out + (size_t)g * sliceN;

    float di = dinv[node];
    uint vs = ((const uint*)(Tg + (size_t)node * 16))[k];
    float sw = di * di;
    float a0 = sw * __uint_as_float(vs << 16);
    float a1 = sw * __uint_as_float(vs & 0xffff0000u);

    int e = row_start[node], end = row_start[node + 1];
    for (; e < end; e += 4) {
        uint c[4], v[4];
        float nn[4];
#pragma unroll
        for (int q = 0; q < 4; q++) {
            if (e + q < end) {
                c[q] = __builtin_nontemporal_load(&csr[e + q]);
                nn[q] = q15f(c[q] & 0x7FFFu);
            } else {
                c[q] = 0; nn[q] = 0.f;
            }
            v[q] = ((const uint*)(Tg + (size_t)(c[q] >> 15) * 16))[k];
        }
#pragma unroll
        for (int q = 0; q < 4; q++) {
            a0 = fmaf(nn[q], __uint_as_float(v[q] << 16), a0);
            a1 = fmaf(nn[q], __uint_as_float(v[q] & 0xffff0000u), a1);
        }
    }

    int col = g * 16 + k * 2;
    a0 = fmaxf(a0 + bias[col], 0.f);
    a1 = fmaxf(a1 + bias[col + 1], 0.f);
    uint o = (uint)f2bf(a0) | ((uint)f2bf(a1) << 16);
    __builtin_nontemporal_store(o, &((uint*)(Hg + (size_t)node * 16))[k]);
}

// ---------------- scalarized row-major agg core (layer 3) ----------------
__device__ __forceinline__ void agg_core(const ushort* __restrict__ T,
                                         const uint* __restrict__ csr,
                                         float di, int beg, int end, int col,
                                         float& a0, float& a1) {
    int lane = threadIdx.x & 63;
    for (int e = beg; e < end; e += 16) {
        int li = e + (lane & 15);
        uint myc = csr[li < end ? li : end - 1];
        uint v[16];
        float nn[16];
#pragma unroll
        for (int q = 0; q < 16; q++) {
            uint c = __builtin_amdgcn_readlane(myc, q);
            nn[q] = (e + q < end) ? q15f(c & 0x7FFFu) : 0.f;
            v[q] = *(const uint*)(T + (size_t)(c >> 15) * D + col);
        }
#pragma unroll
        for (int q = 0; q < 16; q++) {
            a0 = fmaf(nn[q], __uint_as_float(v[q] << 16), a0);
            a1 = fmaf(nn[q], __uint_as_float(v[q] & 0xffff0000u), a1);
        }
    }
}

// ---------------- layer-3 aggregation + per-node head dot (row-major T) ----------------
__global__ __launch_bounds__(256) void k_agg_head(const ushort* __restrict__ T,
                                                  const float* __restrict__ dinv,
                                                  const int* __restrict__ row_start,
                                                  const uint* __restrict__ csr,
                                                  const float* __restrict__ bias,
                                                  const float* __restrict__ Wh,
                                                  float2* __restrict__ y, int N) {
    int node = __builtin_amdgcn_readfirstlane(blockIdx.x * 4 + (threadIdx.x >> 6));
    if (node >= N) return;
    int lane = threadIdx.x & 63;
    int col = lane * 2;

    float di = dinv[node];
    uint vs = *(const uint*)(T + (size_t)node * D + col);
    float sw = di * di;
    float a0 = sw * __uint_as_float(vs << 16);
    float a1 = sw * __uint_as_float(vs & 0xffff0000u);

    agg_core(T, csr, di, row_start[node], row_start[node + 1], col, a0, a1);

    a0 = fmaxf(a0 + bias[col], 0.f);
    a1 = fmaxf(a1 + bias[col + 1], 0.f);

    float p0 = a0 * Wh[col * 2 + 0] + a1 * Wh[(col + 1) * 2 + 0];
    float p1 = a0 * Wh[col * 2 + 1] + a1 * Wh[(col + 1) * 2 + 1];
#pragma unroll
    for (int off = 32; off > 0; off >>= 1) {
        p0 += __shfl_xor(p0, off);
        p1 += __shfl_xor(p1, off);
    }
    if (lane == 0) y[node] = make_float2(p0, p1);
}

// ---------------- per-graph segment mean + bias (batch sorted) ----------------
__global__ __launch_bounds__(256) void k_pool2(const float2* __restrict__ y,
                                               const int* __restrict__ batch, int N,
                                               const float* __restrict__ bh,
                                               float* __restrict__ out) {
    int g = blockIdx.x;
    int t = threadIdx.x;
    int lo = 0, hi = N;
    while (lo < hi) { int m = (lo + hi) >> 1; if (batch[m] < g) lo = m + 1; else hi = m; }
    int beg = lo;
    lo = 0; hi = N;
    while (lo < hi) { int m = (lo + hi) >> 1; if (batch[m] < g + 1) lo = m + 1; else hi = m; }
    int endi = lo;

    float s0 = 0.f, s1 = 0.f;
    for (int i = beg + t; i < endi; i += 256) {
        float2 v = y[i];
        s0 += v.x; s1 += v.y;
    }
    __shared__ float r0[256], r1[256];
    r0[t] = s0; r1[t] = s1;
    __syncthreads();
    for (int off = 128; off > 0; off >>= 1) {
        if (t < off) { r0[t] += r0[t + off]; r1[t] += r1[t + off]; }
        __syncthreads();
    }
    if (t == 0) {
        float cnt = (float)((endi - beg) > 0 ? (endi - beg) : 1);
        out[g * 2 + 0] = r0[0] / cnt + bh[0];
        out[g * 2 + 1] = r1[0] / cnt + bh[1];
    }
}

extern "C" void kernel_launch(void* const* d_in, const int* in_sizes, int n_in,
                              void* d_out, int out_size, void* d_ws, size_t ws_size,
                              hipStream_t stream) {
    const float* x   = (const float*)d_in[0];
    const int* eidx  = (const int*)d_in[1];
    const int* batch = (const int*)d_in[2];
    const float* W1 = (const float*)d_in[3];
    const float* b1 = (const float*)d_in[4];
    const float* W2 = (const float*)d_in[5];
    const float* b2 = (const float*)d_in[6];
    const float* W3 = (const float*)d_in[7];
    const float* b3 = (const float*)d_in[8];
    const float* Wh = (const float*)d_in[9];
    const float* bh = (const float*)d_in[10];

    int E = in_sizes[1] / 2;
    int N = in_sizes[2];
    int ngraphs = out_size / 2;
    const int* src = eidx;
    const int* dst = eidx + E;
    int nbk = (N + (1 << NB_SHIFT) - 1) >> NB_SHIFT;

    char* ws = (char*)d_ws;
    size_t off = 0;
    auto alloc = [&](size_t bytes) -> void* {
        void* p = ws + off;
        off = (off + bytes + 255) & ~(size_t)255;
        return p;
    };
    ushort* Hbf      = (ushort*)alloc((size_t)N * D * 2);   // sliced [8][N][16]
    ushort* T        = (ushort*)alloc((size_t)N * D * 2);   // sliced (L1/2) or row-major (L3)
    ushort* Wf1      = (ushort*)alloc(32768 * 2);
    ushort* Wf2      = (ushort*)alloc(32768 * 2);
    ushort* Wf3      = (ushort*)alloc(32768 * 2);
    int*    degi     = (int*)alloc((size_t)N * 4);
    float*  dinv     = (float*)alloc((size_t)N * 4);
    int*    row_start= (int*)alloc((size_t)(N + 1) * 4);
    int*    gcur     = (int*)alloc((size_t)nbk * 4);
    int*    bofs     = (int*)alloc(4096);
    float2* y        = (float2*)alloc((size_t)N * 8);
    uint*   csr      = (uint*)alloc((size_t)E * 4);
    uint*   arena    = (uint*)alloc((size_t)nbk * BCAP * 4);
    (void)ws_size;

    hipMemsetAsync(gcur, 0, (size_t)nbk * 4, stream);

    k_bucketA<<<(E + EPB - 1) / EPB, 256, 0, stream>>>(src, dst, E, nbk, gcur, arena);
    k_degB<<<nbk, 256, 0, stream>>>(arena, gcur, N, degi, dinv);

    int nb = (N + 1023) / 1024;
    k_scan1<<<nb, 256, 0, stream>>>(degi, N, bofs);
    k_scan2<<<1, 64, 0, stream>>>(bofs, nb);
    k_scan3<<<nb, 256, 0, stream>>>(degi, N, bofs, row_start, E);

    k_bucketB<<<nbk, 256, 0, stream>>>(arena, gcur, row_start, dinv, N, csr);

    k_wsplit<<<128, 256, 0, stream>>>(W1, Wf1);
    k_wsplit<<<128, 256, 0, stream>>>(W2, Wf2);
    k_wsplit<<<128, 256, 0, stream>>>(W3, Wf3);

    int gemm_grid = (N + 63) / 64;
    int aggs_grid = ((N + 31) / 32) * 8;   // blockIdx = chunk*8 + group
    int agg_grid  = (N + 3) / 4;

    // layer 1: x (f32 row-major) -> T sliced -> H sliced
    k_gemm<0, 1><<<gemm_grid, 256, 0, stream>>>(x, Wf1, T, N);
    k_agg_sliced<<<aggs_grid, 256, 0, stream>>>(T, dinv, row_start, csr, b1, Hbf, N);
    // layer 2: H sliced -> T sliced -> H sliced
    k_gemm<1, 1><<<gemm_grid, 256, 0, stream>>>(Hbf, Wf2, T, N);
    k_agg_sliced<<<aggs_grid, 256, 0, stream>>>(T, dinv, row_start, csr, b2, Hbf, N);
    // layer 3: H sliced -> T row-major -> per-node head dot
    k_gemm<1, 0><<<gemm_grid, 256, 0, stream>>>(Hbf, Wf3, T, N);
    k_agg_head<<<agg_grid, 256, 0, stream>>>(T, dinv, row_start, csr, b3, Wh, y, N);
    k_pool2<<<ngraphs, 256, 0, stream>>>(y, batch, N, bh, (float*)d_out);
}

// Round 12
// 307.864 us; speedup vs baseline: 1.7792x; 1.7792x over previous
//
#include <hip/hip_runtime.h>

// RiskGCN: 3-layer GCNConv (self-loops, sym deg^-1/2 norm) + mean pool + linear head.
// N=100000 nodes, E=1.6M edges, D=128, 256 graphs.
// CSR build: bucket-scatter (k_bucketA) -> per-bucket degree hist (k_degB) ->
// scan -> counting-sort (k_bucketB).
// Per layer: MFMA bf16 GEMM (W split hi/lo; async global_load_lds staging) ->
// row-major CSR gather-agg (bf16 msgs, f32 acc, scalarized 16-deep edge loop
// with csr double-buffer prefetch). Layer 3 fuses per-node head dot; segment
// reduce finishes mean+bias.

#define D 128
#define NB_SHIFT 8            // 256 nodes per bucket
#define BCAP 8192             // arena stride per bucket; mean 4096, 64 sigma headroom
#define EPB 4096              // edges per block in bucket pass A (391 blocks)
// NOTE: packing assumes N <= 2^17 and nodes-per-bucket <= 256.

typedef unsigned int uint;
typedef unsigned short ushort;
typedef __attribute__((ext_vector_type(8))) short short8;
typedef __attribute__((ext_vector_type(4))) float f32x4;

__device__ __forceinline__ ushort f2bf(float f) {
    uint u = __float_as_uint(f);
    uint r = (u + 0x7fffu + ((u >> 16) & 1u)) >> 16;   // RNE
    return (ushort)r;
}
__device__ __forceinline__ float bf2f(ushort b) {
    return __uint_as_float(((uint)b) << 16);
}
// 15-bit float norm decode: 5 LSBs of exponent + 10 mantissa bits, exp base 96.
__device__ __forceinline__ float q15f(uint q) {
    return __uint_as_float(0x30000000u | (q << 13));
}

// async 16B global->LDS copy (lds dest is wave-uniform base; HW adds lane*16)
__device__ __forceinline__ void async_cp16(const ushort* g, ushort* lds_uniform) {
    __builtin_amdgcn_global_load_lds(
        (const __attribute__((address_space(1))) unsigned int*)g,
        (__attribute__((address_space(3))) unsigned int*)lds_uniform,
        16, 0, 0);
}

// ---------------- bucket pass A: scatter edges into per-bucket arenas ----------------
// Entry: (dlocal << 17) | src.
__global__ __launch_bounds__(256) void k_bucketA(const int* __restrict__ src,
                                                 const int* __restrict__ dst, int E,
                                                 int nbk, int* __restrict__ gcur,
                                                 uint* __restrict__ arena) {
    __shared__ int hist[512];
    __shared__ int rbase[512];
    int t = threadIdx.x;
    int e0 = blockIdx.x * EPB;
    int e1 = min(e0 + EPB, E);
    for (int i = t; i < nbk; i += 256) hist[i] = 0;
    __syncthreads();
    for (int e = e0 + t; e < e1; e += 256)
        atomicAdd(&hist[dst[e] >> NB_SHIFT], 1);
    __syncthreads();
    for (int i = t; i < nbk; i += 256) {
        int c = hist[i];
        rbase[i] = (c > 0) ? atomicAdd(&gcur[i], c) : 0;
        hist[i] = 0;   // reuse as local cursor
    }
    __syncthreads();
    for (int e = e0 + t; e < e1; e += 256) {
        int d = dst[e];
        int s = src[e];
        int b = d >> NB_SHIFT;
        int pos = rbase[b] + atomicAdd(&hist[b], 1);
        if (pos < BCAP)
            arena[(size_t)b * BCAP + pos] =
                ((uint)(d & ((1 << NB_SHIFT) - 1)) << 17) | (uint)s;
    }
}

// ---------------- per-bucket degree histogram ----------------
__global__ __launch_bounds__(256) void k_degB(const uint* __restrict__ arena,
                                              const int* __restrict__ gcur, int N,
                                              int* __restrict__ degi,
                                              float* __restrict__ dinv) {
    int b = blockIdx.x;
    int t = threadIdx.x;
    __shared__ int hist[256];
    hist[t] = 0;
    __syncthreads();
    int cnt = min(gcur[b], BCAP);
    const uint* seg = arena + (size_t)b * BCAP;
    for (int i = t; i < cnt; i += 256)
        atomicAdd(&hist[seg[i] >> 17], 1);
    __syncthreads();
    int node = (b << NB_SHIFT) + t;
    if (node < N) {
        int c = hist[t];
        degi[node] = c;
        dinv[node] = rsqrtf((float)(c + 1));   // +1 self-loop
    }
}

// ---------------- exclusive scan of degi -> row_start ----------------
__global__ void k_scan1(const int* __restrict__ cnt, int N, int* __restrict__ bsum) {
    __shared__ int sdata[256];
    int t = threadIdx.x;
    int base = blockIdx.x * 1024 + t * 4;
    int s = 0;
#pragma unroll
    for (int j = 0; j < 4; j++) { int i = base + j; if (i < N) s += cnt[i]; }
    sdata[t] = s; __syncthreads();
    for (int off = 128; off > 0; off >>= 1) {
        if (t < off) sdata[t] += sdata[t + off];
        __syncthreads();
    }
    if (t == 0) bsum[blockIdx.x] = sdata[0];
}

__global__ void k_scan2(int* __restrict__ bsum, int nb) {
    if (threadIdx.x == 0) {
        int run = 0;
        for (int b = 0; b < nb; b++) { int v = bsum[b]; bsum[b] = run; run += v; }
    }
}

__global__ void k_scan3(const int* __restrict__ cnt, int N, const int* __restrict__ bofs,
                        int* __restrict__ row_start, int E) {
    __shared__ int sdata[256];
    int t = threadIdx.x;
    int base = blockIdx.x * 1024 + t * 4;
    int v[4]; int s = 0;
#pragma unroll
    for (int j = 0; j < 4; j++) { int i = base + j; v[j] = (i < N) ? cnt[i] : 0; s += v[j]; }
    sdata[t] = s; __syncthreads();
    for (int off = 1; off < 256; off <<= 1) {
        int x = (t >= off) ? sdata[t - off] : 0;
        __syncthreads();
        sdata[t] += x;
        __syncthreads();
    }
    int excl = (t == 0) ? 0 : sdata[t - 1];
    int run = bofs[blockIdx.x] + excl;
#pragma unroll
    for (int j = 0; j < 4; j++) {
        int i = base + j;
        if (i < N) row_start[i] = run;
        run += v[j];
    }
    if (blockIdx.x == 0 && t == 0) row_start[N] = E;
}

// ---------------- bucket pass B: counting-sort bucket into CSR via LDS ----------------
__global__ __launch_bounds__(256) void k_bucketB(const uint* __restrict__ arena,
                                                 const int* __restrict__ gcur,
                                                 const int* __restrict__ row_start,
                                                 const float* __restrict__ dinv,
                                                 int N, uint* __restrict__ csr) {
    int b = blockIdx.x;
    int t = threadIdx.x;
    int n0 = b << NB_SHIFT;
    int nn = min(1 << NB_SHIFT, N - n0);
    __shared__ float sdinv[256];
    __shared__ int sstart[256];
    __shared__ int scur[256];
    __shared__ uint sout[BCAP];   // 32 KB
    for (int i = t; i < nn; i += 256) {
        sdinv[i]  = dinv[n0 + i];
        sstart[i] = row_start[n0 + i];
        scur[i]   = 0;
    }
    __syncthreads();
    int cnt = min(gcur[b], BCAP);
    int csr0 = sstart[0];
    for (int i = t; i < cnt; i += 256) {
        uint en = arena[(size_t)b * BCAP + i];
        int dl = en >> 17;
        int s  = en & 0x1FFFF;
        float nrm = dinv[s] * sdinv[dl];
        uint q = ((__float_as_uint(nrm) + 0x1000u) >> 13) & 0x7FFFu;
        int pos = atomicAdd(&scur[dl], 1);
        sout[(sstart[dl] - csr0) + pos] = ((uint)s << 15) | q;
    }
    __syncthreads();
    for (int i = t; i < cnt; i += 256)
        csr[csr0 + i] = sout[i];
}

// ---------------- W split+fragment for all 3 layers in one launch ----------------
// Wf layout per weight: [h][kt][nt][lane][8] bf16, 32768 entries.
__global__ void k_wsplit3(const float* __restrict__ W1, const float* __restrict__ W2,
                          const float* __restrict__ W3, ushort* __restrict__ Wf) {
    int gidx = blockIdx.x * blockDim.x + threadIdx.x;   // 98304 total
    if (gidx >= 3 * 32768) return;
    int which = gidx >> 15;
    int idx = gidx & 32767;
    const float* W = (which == 0) ? W1 : (which == 1) ? W2 : W3;
    int i  = idx & 7;
    int l  = (idx >> 3) & 63;
    int nt = (idx >> 9) & 7;
    int kt = (idx >> 12) & 3;
    int h  = idx >> 14;
    int k = kt * 32 + (l >> 4) * 8 + i;
    int n = nt * 16 + (l & 15);
    float w = W[k * D + n];
    ushort hi = f2bf(w);
    ushort v = (h == 0) ? hi : f2bf(w - bf2f(hi));
    Wf[gidx] = v;
}

// ---------------- MFMA GEMM: T_bf16[N x 128] = A[N x 128] @ W ----------------
// 256 thr (4 waves), 64-row tile. Wave w owns column tiles nt = 2w, 2w+1; its 16
// B-fragments are preloaded once, A streamed from swizzled LDS.
// AF32 (layer 1): explicit staging with f32->bf16 convert.
// bf16 input: async global_load_lds (16B/lane), linear LDS dest, source column
// pre-swizzled so the ds_read XOR pattern is preserved (both-sides rule).
template <bool AF32>
__global__ __launch_bounds__(256) void k_gemm(const void* __restrict__ Ain,
                                              const ushort* __restrict__ Wf,
                                              ushort* __restrict__ out, int N) {
    __shared__ ushort As[64 * D];   // 16 KB, swizzled
    int t = threadIdx.x;
    int rowb = blockIdx.x * 64;

    if (AF32) {
        const float* A = (const float*)Ain;
#pragma unroll
        for (int i = 0; i < 8; i++) {
            int u = i * 256 + t;
            int row = u >> 5, c4 = u & 31;
            int grow = rowb + row;
            float4 v = make_float4(0.f, 0.f, 0.f, 0.f);
            if (grow < N) v = *(const float4*)(A + (size_t)grow * D + c4 * 4);
            uint2 p;
            p.x = (uint)f2bf(v.x) | ((uint)f2bf(v.y) << 16);
            p.y = (uint)f2bf(v.z) | ((uint)f2bf(v.w) << 16);
            int byteoff = row * 256 + ((c4 * 8) ^ ((row & 7) << 4));
            *(uint2*)((char*)As + byteoff) = p;
        }
    } else {
        const ushort* A = (const ushort*)Ain;
        // 1024 chunks of 16B, linear in LDS; chunk u = (row=u>>4, c'=u&15);
        // source chunk c = c' ^ (row&7) (inverse of the read-side XOR).
#pragma unroll
        for (int i = 0; i < 4; i++) {
            int u = i * 256 + t;
            int row = u >> 4, cp = u & 15;
            int grow = rowb + row;
            if (grow >= N) grow = N - 1;          // clamp; rows discarded at store
            int gc = cp ^ (row & 7);
            const ushort* gp = A + (size_t)grow * D + gc * 8;
            ushort* lb = As + (size_t)(i * 256 + (t & 192)) * 8;
            async_cp16(gp, lb);
        }
        asm volatile("s_waitcnt vmcnt(0)" ::: "memory");
    }
    __syncthreads();

    int wave = t >> 6, lane = t & 63;
    const short8* Wf8 = (const short8*)Wf;

    short8 bhi[2][4], blo[2][4];
#pragma unroll
    for (int j = 0; j < 2; j++) {
        int nt = wave * 2 + j;
#pragma unroll
        for (int kt = 0; kt < 4; kt++) {
            bhi[j][kt] = Wf8[(size_t)((0 * 4 + kt) * 8 + nt) * 64 + lane];
            blo[j][kt] = Wf8[(size_t)((1 * 4 + kt) * 8 + nt) * 64 + lane];
        }
    }

    f32x4 acc[4][2];
#pragma unroll
    for (int m = 0; m < 4; m++)
#pragma unroll
        for (int j = 0; j < 2; j++) acc[m][j] = (f32x4){0.f, 0.f, 0.f, 0.f};

#pragma unroll
    for (int m = 0; m < 4; m++) {
        int r = m * 16 + (lane & 15);
#pragma unroll
        for (int kt = 0; kt < 4; kt++) {
            int raw = kt * 64 + (lane >> 4) * 16;
            short8 a = *(const short8*)((const char*)As + r * 256 + (raw ^ ((r & 7) << 4)));
#pragma unroll
            for (int j = 0; j < 2; j++) {
                acc[m][j] = __builtin_amdgcn_mfma_f32_16x16x32_bf16(a, bhi[j][kt], acc[m][j], 0, 0, 0);
                acc[m][j] = __builtin_amdgcn_mfma_f32_16x16x32_bf16(a, blo[j][kt], acc[m][j], 0, 0, 0);
            }
        }
    }

    // C/D: col = lane&15, row = (lane>>4)*4 + jj
#pragma unroll
    for (int m = 0; m < 4; m++) {
#pragma unroll
        for (int j = 0; j < 2; j++) {
            int colb = (wave * 2 + j) * 16 + (lane & 15);
#pragma unroll
            for (int jj = 0; jj < 4; jj++) {
                int grow = rowb + m * 16 + (lane >> 4) * 4 + jj;
                if (grow < N)
                    out[(size_t)grow * D + colb] = f2bf(acc[m][j][jj]);
            }
        }
    }
}

// ---------------- scalarized node aggregation core (csr double-buffered) ----------------
// One wave per node, lane covers 2 cols. 16 csr entries fetched by one vector
// load (lanes 0-15); next batch's load issued before current batch's gathers.
__device__ __forceinline__ void agg_core(const ushort* __restrict__ T,
                                         const uint* __restrict__ csr,
                                         int beg, int end, int col,
                                         float& a0, float& a1) {
    if (beg >= end) return;
    int lane16 = threadIdx.x & 15;
    uint cur = csr[min(beg + lane16, end - 1)];
    for (int e = beg; e < end; e += 16) {
        uint nxt = 0;
        int en = e + 16;
        if (en < end) nxt = csr[min(en + lane16, end - 1)];
        uint v[16];
        float nn[16];
#pragma unroll
        for (int q = 0; q < 16; q++) {
            uint c = __builtin_amdgcn_readlane(cur, q);
            nn[q] = (e + q < end) ? q15f(c & 0x7FFFu) : 0.f;
            v[q] = *(const uint*)(T + (size_t)(c >> 15) * D + col);
        }
#pragma unroll
        for (int q = 0; q < 16; q++) {
            a0 = fmaf(nn[q], __uint_as_float(v[q] << 16), a0);
            a1 = fmaf(nn[q], __uint_as_float(v[q] & 0xffff0000u), a1);
        }
        cur = nxt;
    }
}

// ---------------- aggregation: Hbf[i] = relu( sum_j nrm*T[j] + di^2*T[i] + b ) ----------------
__global__ __launch_bounds__(256) void k_agg(const ushort* __restrict__ T,
                                             const float* __restrict__ dinv,
                                             const int* __restrict__ row_start,
                                             const uint* __restrict__ csr,
                                             const float* __restrict__ bias,
                                             ushort* __restrict__ out, int N) {
    int node = __builtin_amdgcn_readfirstlane(blockIdx.x * 4 + (threadIdx.x >> 6));
    if (node >= N) return;
    int lane = threadIdx.x & 63;
    int col = lane * 2;

    float di = dinv[node];
    uint vs = *(const uint*)(T + (size_t)node * D + col);
    float sw = di * di;
    float a0 = sw * __uint_as_float(vs << 16);
    float a1 = sw * __uint_as_float(vs & 0xffff0000u);

    agg_core(T, csr, row_start[node], row_start[node + 1], col, a0, a1);

    a0 = fmaxf(a0 + bias[col], 0.f);
    a1 = fmaxf(a1 + bias[col + 1], 0.f);
    ushort2 o; o.x = f2bf(a0); o.y = f2bf(a1);
    *(ushort2*)(out + (size_t)node * D + col) = o;
}

// ---------------- layer-3 aggregation + per-node head dot (no atomics) ----------------
__global__ __launch_bounds__(256) void k_agg_head(const ushort* __restrict__ T,
                                                  const float* __restrict__ dinv,
                                                  const int* __restrict__ row_start,
                                                  const uint* __restrict__ csr,
                                                  const float* __restrict__ bias,
                                                  const float* __restrict__ Wh,
                                                  float2* __restrict__ y, int N) {
    int node = __builtin_amdgcn_readfirstlane(blockIdx.x * 4 + (threadIdx.x >> 6));
    if (node >= N) return;
    int lane = threadIdx.x & 63;
    int col = lane * 2;

    float di = dinv[node];
    uint vs = *(const uint*)(T + (size_t)node * D + col);
    float sw = di * di;
    float a0 = sw * __uint_as_float(vs << 16);
    float a1 = sw * __uint_as_float(vs & 0xffff0000u);

    agg_core(T, csr, row_start[node], row_start[node + 1], col, a0, a1);

    a0 = fmaxf(a0 + bias[col], 0.f);
    a1 = fmaxf(a1 + bias[col + 1], 0.f);

    float p0 = a0 * Wh[col * 2 + 0] + a1 * Wh[(col + 1) * 2 + 0];
    float p1 = a0 * Wh[col * 2 + 1] + a1 * Wh[(col + 1) * 2 + 1];
#pragma unroll
    for (int off = 32; off > 0; off >>= 1) {
        p0 += __shfl_xor(p0, off);
        p1 += __shfl_xor(p1, off);
    }
    if (lane == 0) y[node] = make_float2(p0, p1);
}

// ---------------- per-graph segment mean + bias (batch sorted) ----------------
__global__ __launch_bounds__(256) void k_pool2(const float2* __restrict__ y,
                                               const int* __restrict__ batch, int N,
                                               const float* __restrict__ bh,
                                               float* __restrict__ out) {
    int g = blockIdx.x;
    int t = threadIdx.x;
    int lo = 0, hi = N;
    while (lo < hi) { int m = (lo + hi) >> 1; if (batch[m] < g) lo = m + 1; else hi = m; }
    int beg = lo;
    lo = 0; hi = N;
    while (lo < hi) { int m = (lo + hi) >> 1; if (batch[m] < g + 1) lo = m + 1; else hi = m; }
    int endi = lo;

    float s0 = 0.f, s1 = 0.f;
    for (int i = beg + t; i < endi; i += 256) {
        float2 v = y[i];
        s0 += v.x; s1 += v.y;
    }
    __shared__ float r0[256], r1[256];
    r0[t] = s0; r1[t] = s1;
    __syncthreads();
    for (int off = 128; off > 0; off >>= 1) {
        if (t < off) { r0[t] += r0[t + off]; r1[t] += r1[t + off]; }
        __syncthreads();
    }
    if (t == 0) {
        float cnt = (float)((endi - beg) > 0 ? (endi - beg) : 1);
        out[g * 2 + 0] = r0[0] / cnt + bh[0];
        out[g * 2 + 1] = r1[0] / cnt + bh[1];
    }
}

extern "C" void kernel_launch(void* const* d_in, const int* in_sizes, int n_in,
                              void* d_out, int out_size, void* d_ws, size_t ws_size,
                              hipStream_t stream) {
    const float* x   = (const float*)d_in[0];
    const int* eidx  = (const int*)d_in[1];
    const int* batch = (const int*)d_in[2];
    const float* W1 = (const float*)d_in[3];
    const float* b1 = (const float*)d_in[4];
    const float* W2 = (const float*)d_in[5];
    const float* b2 = (const float*)d_in[6];
    const float* W3 = (const float*)d_in[7];
    const float* b3 = (const float*)d_in[8];
    const float* Wh = (const float*)d_in[9];
    const float* bh = (const float*)d_in[10];

    int E = in_sizes[1] / 2;
    int N = in_sizes[2];
    int ngraphs = out_size / 2;
    const int* src = eidx;
    const int* dst = eidx + E;
    int nbk = (N + (1 << NB_SHIFT) - 1) >> NB_SHIFT;

    char* ws = (char*)d_ws;
    size_t off = 0;
    auto alloc = [&](size_t bytes) -> void* {
        void* p = ws + off;
        off = (off + bytes + 255) & ~(size_t)255;
        return p;
    };
    ushort* Hbf      = (ushort*)alloc((size_t)N * D * 2);
    ushort* T        = (ushort*)alloc((size_t)N * D * 2);
    ushort* Wf       = (ushort*)alloc(3 * 32768 * 2);
    int*    degi     = (int*)alloc((size_t)N * 4);
    float*  dinv     = (float*)alloc((size_t)N * 4);
    int*    row_start= (int*)alloc((size_t)(N + 1) * 4);
    int*    gcur     = (int*)alloc((size_t)nbk * 4);
    int*    bofs     = (int*)alloc(4096);
    float2* y        = (float2*)alloc((size_t)N * 8);
    uint*   csr      = (uint*)alloc((size_t)E * 4);
    uint*   arena    = (uint*)alloc((size_t)nbk * BCAP * 4);
    (void)ws_size;

    hipMemsetAsync(gcur, 0, (size_t)nbk * 4, stream);

    k_bucketA<<<(E + EPB - 1) / EPB, 256, 0, stream>>>(src, dst, E, nbk, gcur, arena);
    k_degB<<<nbk, 256, 0, stream>>>(arena, gcur, N, degi, dinv);

    int nb = (N + 1023) / 1024;
    k_scan1<<<nb, 256, 0, stream>>>(degi, N, bofs);
    k_scan2<<<1, 64, 0, stream>>>(bofs, nb);
    k_scan3<<<nb, 256, 0, stream>>>(degi, N, bofs, row_start, E);

    k_bucketB<<<nbk, 256, 0, stream>>>(arena, gcur, row_start, dinv, N, csr);

    k_wsplit3<<<384, 256, 0, stream>>>(W1, W2, W3, Wf);

    int gemm_grid = (N + 63) / 64;
    int agg_grid = (N + 3) / 4;

    // layer 1
    k_gemm<true><<<gemm_grid, 256, 0, stream>>>(x, Wf, T, N);
    k_agg<<<agg_grid, 256, 0, stream>>>(T, dinv, row_start, csr, b1, Hbf, N);
    // layer 2
    k_gemm<false><<<gemm_grid, 256, 0, stream>>>(Hbf, Wf + 32768, T, N);
    k_agg<<<agg_grid, 256, 0, stream>>>(T, dinv, row_start, csr, b2, Hbf, N);
    // layer 3
    k_gemm<false><<<gemm_grid, 256, 0, stream>>>(Hbf, Wf + 65536, T, N);
    k_agg_head<<<agg_grid, 256, 0, stream>>>(T, dinv, row_start, csr, b3, Wh, y, N);
    k_pool2<<<ngraphs, 256, 0, stream>>>(y, batch, N, bh, (float*)d_out);
}

// Round 13
// 289.201 us; speedup vs baseline: 1.8941x; 1.0645x over previous
//
#include <hip/hip_runtime.h>

// RiskGCN: 3-layer GCNConv (self-loops, sym deg^-1/2 norm) + mean pool + linear head.
// N=100000 nodes, E=1.6M edges, D=128, 256 graphs.
// Build: fused [bucket-scatter || layer-1 GEMM] -> 1-block bucket-base scan ->
// per-bucket hist+scan (dinv,row_start) -> counting-sort to CSR.
// Per layer: MFMA bf16 GEMM (W split hi/lo; async global_load_lds staging) ->
// row-major CSR gather-agg (bf16 msgs, f32 acc, scalarized 16-deep edge loop).
// Layer 3 fuses per-node head dot; segment reduce finishes mean+bias.

#define D 128
#define NB_SHIFT 8            // 256 nodes per bucket
#define BCAP 8192             // arena stride per bucket; mean 4096, 64 sigma headroom
#define EPB 4096              // edges per block in bucket pass A (391 blocks)
// NOTE: packing assumes N <= 2^17 and nodes-per-bucket <= 256.

typedef unsigned int uint;
typedef unsigned short ushort;
typedef __attribute__((ext_vector_type(8))) short short8;
typedef __attribute__((ext_vector_type(4))) float f32x4;

__device__ __forceinline__ ushort f2bf(float f) {
    uint u = __float_as_uint(f);
    uint r = (u + 0x7fffu + ((u >> 16) & 1u)) >> 16;   // RNE
    return (ushort)r;
}
__device__ __forceinline__ float bf2f(ushort b) {
    return __uint_as_float(((uint)b) << 16);
}
// 15-bit float norm decode: 5 LSBs of exponent + 10 mantissa bits, exp base 96.
__device__ __forceinline__ float q15f(uint q) {
    return __uint_as_float(0x30000000u | (q << 13));
}

// async 16B global->LDS copy (lds dest is wave-uniform base; HW adds lane*16)
__device__ __forceinline__ void async_cp16(const ushort* g, ushort* lds_uniform) {
    __builtin_amdgcn_global_load_lds(
        (const __attribute__((address_space(1))) unsigned int*)g,
        (__attribute__((address_space(3))) unsigned int*)lds_uniform,
        16, 0, 0);
}

// ---------------- bucket scatter body (pass A) ----------------
// Entry: (dlocal << 17) | src.
__device__ __forceinline__ void bucketA_body(const int* __restrict__ src,
                                             const int* __restrict__ dst, int E,
                                             int nbk, int* __restrict__ gcur,
                                             uint* __restrict__ arena, int bid,
                                             int* hist, int* rbase) {
    int t = threadIdx.x;
    int e0 = bid * EPB;
    int e1 = min(e0 + EPB, E);
    for (int i = t; i < nbk; i += 256) hist[i] = 0;
    __syncthreads();
    for (int e = e0 + t; e < e1; e += 256)
        atomicAdd(&hist[dst[e] >> NB_SHIFT], 1);
    __syncthreads();
    for (int i = t; i < nbk; i += 256) {
        int c = hist[i];
        rbase[i] = (c > 0) ? atomicAdd(&gcur[i], c) : 0;
        hist[i] = 0;   // reuse as local cursor
    }
    __syncthreads();
    for (int e = e0 + t; e < e1; e += 256) {
        int d = dst[e];
        int s = src[e];
        int b = d >> NB_SHIFT;
        int pos = rbase[b] + atomicAdd(&hist[b], 1);
        if (pos < BCAP)
            arena[(size_t)b * BCAP + pos] =
                ((uint)(d & ((1 << NB_SHIFT) - 1)) << 17) | (uint)s;
    }
}

// ---------------- MFMA GEMM body: T_bf16[rowb..rowb+64) = A @ W ----------------
// 4 waves; wave w owns column tiles nt = 2w, 2w+1; 16 B-fragments preloaded;
// A via swizzled LDS (async global_load_lds for bf16 input, pre-swizzled src).
template <bool AF32>
__device__ __forceinline__ void gemm_body(const void* __restrict__ Ain,
                                          const ushort* __restrict__ Wf,
                                          ushort* __restrict__ out, int N,
                                          int rowb, ushort* As) {
    int t = threadIdx.x;

    if (AF32) {
        const float* A = (const float*)Ain;
#pragma unroll
        for (int i = 0; i < 8; i++) {
            int u = i * 256 + t;
            int row = u >> 5, c4 = u & 31;
            int grow = rowb + row;
            float4 v = make_float4(0.f, 0.f, 0.f, 0.f);
            if (grow < N) v = *(const float4*)(A + (size_t)grow * D + c4 * 4);
            uint2 p;
            p.x = (uint)f2bf(v.x) | ((uint)f2bf(v.y) << 16);
            p.y = (uint)f2bf(v.z) | ((uint)f2bf(v.w) << 16);
            int byteoff = row * 256 + ((c4 * 8) ^ ((row & 7) << 4));
            *(uint2*)((char*)As + byteoff) = p;
        }
    } else {
        const ushort* A = (const ushort*)Ain;
        // 1024 chunks of 16B, linear in LDS; chunk u = (row=u>>4, c'=u&15);
        // source chunk c = c' ^ (row&7) (inverse of the read-side XOR).
#pragma unroll
        for (int i = 0; i < 4; i++) {
            int u = i * 256 + t;
            int row = u >> 4, cp = u & 15;
            int grow = rowb + row;
            if (grow >= N) grow = N - 1;          // clamp; rows discarded at store
            int gc = cp ^ (row & 7);
            const ushort* gp = A + (size_t)grow * D + gc * 8;
            ushort* lb = As + (size_t)(i * 256 + (t & 192)) * 8;
            async_cp16(gp, lb);
        }
        asm volatile("s_waitcnt vmcnt(0)" ::: "memory");
    }
    __syncthreads();

    int wave = t >> 6, lane = t & 63;
    const short8* Wf8 = (const short8*)Wf;

    short8 bhi[2][4], blo[2][4];
#pragma unroll
    for (int j = 0; j < 2; j++) {
        int nt = wave * 2 + j;
#pragma unroll
        for (int kt = 0; kt < 4; kt++) {
            bhi[j][kt] = Wf8[(size_t)((0 * 4 + kt) * 8 + nt) * 64 + lane];
            blo[j][kt] = Wf8[(size_t)((1 * 4 + kt) * 8 + nt) * 64 + lane];
        }
    }

    f32x4 acc[4][2];
#pragma unroll
    for (int m = 0; m < 4; m++)
#pragma unroll
        for (int j = 0; j < 2; j++) acc[m][j] = (f32x4){0.f, 0.f, 0.f, 0.f};

#pragma unroll
    for (int m = 0; m < 4; m++) {
        int r = m * 16 + (lane & 15);
#pragma unroll
        for (int kt = 0; kt < 4; kt++) {
            int raw = kt * 64 + (lane >> 4) * 16;
            short8 a = *(const short8*)((const char*)As + r * 256 + (raw ^ ((r & 7) << 4)));
#pragma unroll
            for (int j = 0; j < 2; j++) {
                acc[m][j] = __builtin_amdgcn_mfma_f32_16x16x32_bf16(a, bhi[j][kt], acc[m][j], 0, 0, 0);
                acc[m][j] = __builtin_amdgcn_mfma_f32_16x16x32_bf16(a, blo[j][kt], acc[m][j], 0, 0, 0);
            }
        }
    }

    // C/D: col = lane&15, row = (lane>>4)*4 + jj
#pragma unroll
    for (int m = 0; m < 4; m++) {
#pragma unroll
        for (int j = 0; j < 2; j++) {
            int colb = (wave * 2 + j) * 16 + (lane & 15);
#pragma unroll
            for (int jj = 0; jj < 4; jj++) {
                int grow = rowb + m * 16 + (lane >> 4) * 4 + jj;
                if (grow < N)
                    out[(size_t)grow * D + colb] = f2bf(acc[m][j][jj]);
            }
        }
    }
}

// ---------------- fused: bucket scatter (blocks 0..nA) || layer-1 GEMM ----------------
__global__ __launch_bounds__(256) void k_build_gemm1(const int* __restrict__ src,
                                                     const int* __restrict__ dst, int E,
                                                     int nbk, int* __restrict__ gcur,
                                                     uint* __restrict__ arena, int nA,
                                                     const float* __restrict__ x,
                                                     const ushort* __restrict__ Wf,
                                                     ushort* __restrict__ T, int N) {
    __shared__ ushort As[64 * D];   // 16 KB; bucketA aliases first 4 KB
    if ((int)blockIdx.x < nA) {
        int* hist = (int*)As;
        int* rbase = hist + 512;
        bucketA_body(src, dst, E, nbk, gcur, arena, blockIdx.x, hist, rbase);
    } else {
        gemm_body<true>(x, Wf, T, N, (blockIdx.x - nA) * 64, As);
    }
}

// ---------------- standalone GEMM (layers 2-3) ----------------
template <bool AF32>
__global__ __launch_bounds__(256) void k_gemm(const void* __restrict__ Ain,
                                              const ushort* __restrict__ Wf,
                                              ushort* __restrict__ out, int N) {
    __shared__ ushort As[64 * D];
    gemm_body<AF32>(Ain, Wf, out, N, blockIdx.x * 64, As);
}

// ---------------- 1-block prefix over bucket sums -> bbase; row_start[N]=E ----------------
__global__ void k_scanG(const int* __restrict__ gcur, int nbk, int E,
                        int* __restrict__ bbase, int* __restrict__ row_start, int N) {
    __shared__ int s[512];
    int t = threadIdx.x;
    s[t] = (t < nbk) ? gcur[t] : 0;
    __syncthreads();
    for (int off = 1; off < 512; off <<= 1) {
        int x = (t >= off) ? s[t - off] : 0;
        __syncthreads();
        s[t] += x;
        __syncthreads();
    }
    if (t < nbk) bbase[t] = s[t] - gcur[t];   // exclusive
    if (t == 0) row_start[N] = E;
}

// ---------------- per-bucket degree hist + LDS scan -> dinv, row_start ----------------
__global__ __launch_bounds__(256) void k_degB2(const uint* __restrict__ arena,
                                               const int* __restrict__ gcur,
                                               const int* __restrict__ bbase, int N,
                                               float* __restrict__ dinv,
                                               int* __restrict__ row_start) {
    int b = blockIdx.x;
    int t = threadIdx.x;
    __shared__ int hist[256];
    __shared__ int sc[256];
    hist[t] = 0;
    __syncthreads();
    int cnt = min(gcur[b], BCAP);
    const uint* seg = arena + (size_t)b * BCAP;
    for (int i = t; i < cnt; i += 256)
        atomicAdd(&hist[seg[i] >> 17], 1);
    __syncthreads();
    int c = hist[t];
    sc[t] = c;
    __syncthreads();
    for (int off = 1; off < 256; off <<= 1) {
        int x = (t >= off) ? sc[t - off] : 0;
        __syncthreads();
        sc[t] += x;
        __syncthreads();
    }
    int node = (b << NB_SHIFT) + t;
    if (node < N) {
        dinv[node] = rsqrtf((float)(c + 1));      // +1 self-loop
        row_start[node] = bbase[b] + sc[t] - c;   // exclusive within bucket
    }
}

// ---------------- bucket pass B: counting-sort bucket into CSR via LDS ----------------
__global__ __launch_bounds__(256) void k_bucketB(const uint* __restrict__ arena,
                                                 const int* __restrict__ gcur,
                                                 const int* __restrict__ row_start,
                                                 const float* __restrict__ dinv,
                                                 int N, uint* __restrict__ csr) {
    int b = blockIdx.x;
    int t = threadIdx.x;
    int n0 = b << NB_SHIFT;
    int nn = min(1 << NB_SHIFT, N - n0);
    __shared__ float sdinv[256];
    __shared__ int sstart[256];
    __shared__ int scur[256];
    __shared__ uint sout[BCAP];   // 32 KB
    for (int i = t; i < nn; i += 256) {
        sdinv[i]  = dinv[n0 + i];
        sstart[i] = row_start[n0 + i];
        scur[i]   = 0;
    }
    __syncthreads();
    int cnt = min(gcur[b], BCAP);
    int csr0 = sstart[0];
    for (int i = t; i < cnt; i += 256) {
        uint en = arena[(size_t)b * BCAP + i];
        int dl = en >> 17;
        int s  = en & 0x1FFFF;
        float nrm = dinv[s] * sdinv[dl];
        uint q = ((__float_as_uint(nrm) + 0x1000u) >> 13) & 0x7FFFu;
        int pos = atomicAdd(&scur[dl], 1);
        sout[(sstart[dl] - csr0) + pos] = ((uint)s << 15) | q;
    }
    __syncthreads();
    for (int i = t; i < cnt; i += 256)
        csr[csr0 + i] = sout[i];
}

// ---------------- W split+fragment for all 3 layers in one launch ----------------
__global__ void k_wsplit3(const float* __restrict__ W1, const float* __restrict__ W2,
                          const float* __restrict__ W3, ushort* __restrict__ Wf) {
    int gidx = blockIdx.x * blockDim.x + threadIdx.x;   // 98304 total
    if (gidx >= 3 * 32768) return;
    int which = gidx >> 15;
    int idx = gidx & 32767;
    const float* W = (which == 0) ? W1 : (which == 1) ? W2 : W3;
    int i  = idx & 7;
    int l  = (idx >> 3) & 63;
    int nt = (idx >> 9) & 7;
    int kt = (idx >> 12) & 3;
    int h  = idx >> 14;
    int k = kt * 32 + (l >> 4) * 8 + i;
    int n = nt * 16 + (l & 15);
    float w = W[k * D + n];
    ushort hi = f2bf(w);
    ushort v = (h == 0) ? hi : f2bf(w - bf2f(hi));
    Wf[gidx] = v;
}

// ---------------- scalarized node aggregation core (csr double-buffered) ----------------
__device__ __forceinline__ void agg_core(const ushort* __restrict__ T,
                                         const uint* __restrict__ csr,
                                         int beg, int end, int col,
                                         float& a0, float& a1) {
    if (beg >= end) return;
    int lane16 = threadIdx.x & 15;
    uint cur = csr[min(beg + lane16, end - 1)];
    for (int e = beg; e < end; e += 16) {
        uint nxt = 0;
        int en = e + 16;
        if (en < end) nxt = csr[min(en + lane16, end - 1)];
        uint v[16];
        float nn[16];
#pragma unroll
        for (int q = 0; q < 16; q++) {
            uint c = __builtin_amdgcn_readlane(cur, q);
            nn[q] = (e + q < end) ? q15f(c & 0x7FFFu) : 0.f;
            v[q] = *(const uint*)(T + (size_t)(c >> 15) * D + col);
        }
#pragma unroll
        for (int q = 0; q < 16; q++) {
            a0 = fmaf(nn[q], __uint_as_float(v[q] << 16), a0);
            a1 = fmaf(nn[q], __uint_as_float(v[q] & 0xffff0000u), a1);
        }
        cur = nxt;
    }
}

// ---------------- aggregation: Hbf[i] = relu( sum_j nrm*T[j] + di^2*T[i] + b ) ----------------
__global__ __launch_bounds__(256) void k_agg(const ushort* __restrict__ T,
                                             const float* __restrict__ dinv,
                                             const int* __restrict__ row_start,
                                             const uint* __restrict__ csr,
                                             const float* __restrict__ bias,
                                             ushort* __restrict__ out, int N) {
    int node = __builtin_amdgcn_readfirstlane(blockIdx.x * 4 + (threadIdx.x >> 6));
    if (node >= N) return;
    int lane = threadIdx.x & 63;
    int col = lane * 2;

    float di = dinv[node];
    uint vs = *(const uint*)(T + (size_t)node * D + col);
    float sw = di * di;
    float a0 = sw * __uint_as_float(vs << 16);
    float a1 = sw * __uint_as_float(vs & 0xffff0000u);

    agg_core(T, csr, row_start[node], row_start[node + 1], col, a0, a1);

    a0 = fmaxf(a0 + bias[col], 0.f);
    a1 = fmaxf(a1 + bias[col + 1], 0.f);
    ushort2 o; o.x = f2bf(a0); o.y = f2bf(a1);
    *(ushort2*)(out + (size_t)node * D + col) = o;
}

// ---------------- layer-3 aggregation + per-node head dot (no atomics) ----------------
__global__ __launch_bounds__(256) void k_agg_head(const ushort* __restrict__ T,
                                                  const float* __restrict__ dinv,
                                                  const int* __restrict__ row_start,
                                                  const uint* __restrict__ csr,
                                                  const float* __restrict__ bias,
                                                  const float* __restrict__ Wh,
                                                  float2* __restrict__ y, int N) {
    int node = __builtin_amdgcn_readfirstlane(blockIdx.x * 4 + (threadIdx.x >> 6));
    if (node >= N) return;
    int lane = threadIdx.x & 63;
    int col = lane * 2;

    float di = dinv[node];
    uint vs = *(const uint*)(T + (size_t)node * D + col);
    float sw = di * di;
    float a0 = sw * __uint_as_float(vs << 16);
    float a1 = sw * __uint_as_float(vs & 0xffff0000u);

    agg_core(T, csr, row_start[node], row_start[node + 1], col, a0, a1);

    a0 = fmaxf(a0 + bias[col], 0.f);
    a1 = fmaxf(a1 + bias[col + 1], 0.f);

    float p0 = a0 * Wh[col * 2 + 0] + a1 * Wh[(col + 1) * 2 + 0];
    float p1 = a0 * Wh[col * 2 + 1] + a1 * Wh[(col + 1) * 2 + 1];
#pragma unroll
    for (int off = 32; off > 0; off >>= 1) {
        p0 += __shfl_xor(p0, off);
        p1 += __shfl_xor(p1, off);
    }
    if (lane == 0) y[node] = make_float2(p0, p1);
}

// ---------------- per-graph segment mean + bias (batch sorted) ----------------
__global__ __launch_bounds__(256) void k_pool2(const float2* __restrict__ y,
                                               const int* __restrict__ batch, int N,
                                               const float* __restrict__ bh,
                                               float* __restrict__ out) {
    int g = blockIdx.x;
    int t = threadIdx.x;
    int lo = 0, hi = N;
    while (lo < hi) { int m = (lo + hi) >> 1; if (batch[m] < g) lo = m + 1; else hi = m; }
    int beg = lo;
    lo = 0; hi = N;
    while (lo < hi) { int m = (lo + hi) >> 1; if (batch[m] < g + 1) lo = m + 1; else hi = m; }
    int endi = lo;

    float s0 = 0.f, s1 = 0.f;
    for (int i = beg + t; i < endi; i += 256) {
        float2 v = y[i];
        s0 += v.x; s1 += v.y;
    }
    __shared__ float r0[256], r1[256];
    r0[t] = s0; r1[t] = s1;
    __syncthreads();
    for (int off = 128; off > 0; off >>= 1) {
        if (t < off) { r0[t] += r0[t + off]; r1[t] += r1[t + off]; }
        __syncthreads();
    }
    if (t == 0) {
        float cnt = (float)((endi - beg) > 0 ? (endi - beg) : 1);
        out[g * 2 + 0] = r0[0] / cnt + bh[0];
        out[g * 2 + 1] = r1[0] / cnt + bh[1];
    }
}

extern "C" void kernel_launch(void* const* d_in, const int* in_sizes, int n_in,
                              void* d_out, int out_size, void* d_ws, size_t ws_size,
                              hipStream_t stream) {
    const float* x   = (const float*)d_in[0];
    const int* eidx  = (const int*)d_in[1];
    const int* batch = (const int*)d_in[2];
    const float* W1 = (const float*)d_in[3];
    const float* b1 = (const float*)d_in[4];
    const float* W2 = (const float*)d_in[5];
    const float* b2 = (const float*)d_in[6];
    const float* W3 = (const float*)d_in[7];
    const float* b3 = (const float*)d_in[8];
    const float* Wh = (const float*)d_in[9];
    const float* bh = (const float*)d_in[10];

    int E = in_sizes[1] / 2;
    int N = in_sizes[2];
    int ngraphs = out_size / 2;
    const int* src = eidx;
    const int* dst = eidx + E;
    int nbk = (N + (1 << NB_SHIFT) - 1) >> NB_SHIFT;

    char* ws = (char*)d_ws;
    size_t off = 0;
    auto alloc = [&](size_t bytes) -> void* {
        void* p = ws + off;
        off = (off + bytes + 255) & ~(size_t)255;
        return p;
    };
    ushort* Hbf      = (ushort*)alloc((size_t)N * D * 2);
    ushort* T        = (ushort*)alloc((size_t)N * D * 2);
    ushort* Wf       = (ushort*)alloc(3 * 32768 * 2);
    float*  dinv     = (float*)alloc((size_t)N * 4);
    int*    row_start= (int*)alloc((size_t)(N + 1) * 4);
    int*    gcur     = (int*)alloc((size_t)nbk * 4);
    int*    bbase    = (int*)alloc((size_t)nbk * 4);
    float2* y        = (float2*)alloc((size_t)N * 8);
    uint*   csr      = (uint*)alloc((size_t)E * 4);
    uint*   arena    = (uint*)alloc((size_t)nbk * BCAP * 4);
    (void)ws_size;

    hipMemsetAsync(gcur, 0, (size_t)nbk * 4, stream);
    k_wsplit3<<<384, 256, 0, stream>>>(W1, W2, W3, Wf);

    int gemm_grid = (N + 63) / 64;
    int agg_grid = (N + 3) / 4;
    int nA = (E + EPB - 1) / EPB;

    // fused: CSR bucket scatter (first nA blocks) || layer-1 GEMM
    k_build_gemm1<<<nA + gemm_grid, 256, 0, stream>>>(src, dst, E, nbk, gcur, arena,
                                                      nA, x, Wf, T, N);
    k_scanG<<<1, 512, 0, stream>>>(gcur, nbk, E, bbase, row_start, N);
    k_degB2<<<nbk, 256, 0, stream>>>(arena, gcur, bbase, N, dinv, row_start);
    k_bucketB<<<nbk, 256, 0, stream>>>(arena, gcur, row_start, dinv, N, csr);

    // layer 1 aggregation
    k_agg<<<agg_grid, 256, 0, stream>>>(T, dinv, row_start, csr, b1, Hbf, N);
    // layer 2
    k_gemm<false><<<gemm_grid, 256, 0, stream>>>(Hbf, Wf + 32768, T, N);
    k_agg<<<agg_grid, 256, 0, stream>>>(T, dinv, row_start, csr, b2, Hbf, N);
    // layer 3
    k_gemm<false><<<gemm_grid, 256, 0, stream>>>(Hbf, Wf + 65536, T, N);
    k_agg_head<<<agg_grid, 256, 0, stream>>>(T, dinv, row_start, csr, b3, Wh, y, N);
    k_pool2<<<ngraphs, 256, 0, stream>>>(y, batch, N, bh, (float*)d_out);
}